// Round 7
// baseline (271.322 us; speedup 1.0000x reference)
//
#include <hip/hip_runtime.h>
#include <math.h>

#define NB 32            // batch
#define DET_BLOCKS 96    // 3 scales * 32 images
#define SEG_BLOCKS 8192  // 32 images * 256 chunks of 256 quads

// ---------- math helpers (match reference semantics) ----------

__device__ __forceinline__ float bce_logits(float x, float y) {
    // max(x,0) - x*y + log1p(exp(-|x|))
    float a = fabsf(x);
    return fmaxf(x, 0.f) - x * y + __logf(1.f + __expf(-a));
}

__device__ __forceinline__ float focal_elt(float x, float t) {
    // t is exactly 0.0 or 1.0 (one-hot)
    float p = 1.f / (1.f + __expf(-x));
    float ce = bce_logits(x, t);
    float p_t = (t > 0.5f) ? p : (1.f - p);
    float a_t = (t > 0.5f) ? 0.25f : 0.75f;
    float om = 1.f - p_t;
    return a_t * om * om * ce;
}

// Block reduction for N floats, blockDim.x == 256 (4 waves of 64).
template <int N>
__device__ void blk_reduce_arr(float* v) {
    __shared__ float sm[N][4];
    int lane = threadIdx.x & 63;
    int wid  = threadIdx.x >> 6;
#pragma unroll
    for (int j = 0; j < N; j++) {
        float x = v[j];
#pragma unroll
        for (int off = 32; off > 0; off >>= 1) x += __shfl_down(x, off, 64);
        if (lane == 0) sm[j][wid] = x;
    }
    __syncthreads();
    if (threadIdx.x == 0) {
#pragma unroll
        for (int j = 0; j < N; j++) {
            float s = 0.f;
#pragma unroll
            for (int w = 0; w < 4; w++) s += sm[j][w];
            v[j] = s;
        }
    }
}

// ---------- seg: standalone, minimal VGPR, max occupancy ----------
// 8192 blocks; block -> (image b, 256-quad chunk). Per thread: 1 int4 mask
// load + 4 channel float4 loads (5 KB in flight per wave), 16 bce terms.
// __launch_bounds__(256, 8): cap at 64 VGPR -> 8 waves/SIMD, 32 waves/CU.

__global__ __launch_bounds__(256, 8) void seg_kernel(
        const float* __restrict__ logits, const int* __restrict__ mask,
        float* __restrict__ partial) {
    const int HW  = 512 * 512;   // px per image
    const int QPI = HW / 4;      // 65536 quads per image
    const int b  = blockIdx.x >> 8;                       // image
    const int hw = ((blockIdx.x & 255) << 8) + threadIdx.x;  // quad in image

    const int4 m4 = ((const int4*)(mask + (size_t)b * HW))[hw];
    const float4* xb = (const float4*)(logits + (size_t)b * 4 * HW) + hw;
    const float4 x0 = xb[0];
    const float4 x1 = xb[QPI];
    const float4 x2 = xb[2 * QPI];
    const float4 x3 = xb[3 * QPI];

    const float t0 = (float)m4.x, t1 = (float)m4.y;
    const float t2 = (float)m4.z, t3 = (float)m4.w;
    float acc;
    acc  = bce_logits(x0.x, t0) + bce_logits(x0.y, t1)
         + bce_logits(x0.z, t2) + bce_logits(x0.w, t3);
    acc += bce_logits(x1.x, t0) + bce_logits(x1.y, t1)
         + bce_logits(x1.z, t2) + bce_logits(x1.w, t3);
    acc += bce_logits(x2.x, t0) + bce_logits(x2.y, t1)
         + bce_logits(x2.z, t2) + bce_logits(x2.w, t3);
    acc += bce_logits(x3.x, t0) + bce_logits(x3.y, t1)
         + bce_logits(x3.z, t2) + bce_logits(x3.w, t3);

    float v[1] = {acc};
    blk_reduce_arr<1>(v);
    if (threadIdx.x == 0) partial[blockIdx.x] = v[0];
}

// ---------- det: standalone, one block per (scale, image) ----------

__global__ __launch_bounds__(256) void det_kernel(
        const float* __restrict__ cls0, const float* __restrict__ cls1, const float* __restrict__ cls2,
        const float* __restrict__ reg0, const float* __restrict__ reg1, const float* __restrict__ reg2,
        const float* __restrict__ cen0, const float* __restrict__ cen1, const float* __restrict__ cen2,
        const float* __restrict__ boxes, const int* __restrict__ labels,
        float* __restrict__ detc) {
    const int s = blockIdx.x >> 5;   // 0..2
    const int b = blockIdx.x & 31;   // 0..31
    int Wd, shift, L; float stride;
    const float *cls, *reg, *cen;
    if (s == 0)      { Wd = 64; shift = 6; L = 4096; stride = 8.f;  cls = cls0; reg = reg0; cen = cen0; }
    else if (s == 1) { Wd = 32; shift = 5; L = 1024; stride = 16.f; cls = cls1; reg = reg1; cen = cen1; }
    else             { Wd = 16; shift = 4; L = 256;  stride = 32.f; cls = cls2; reg = reg2; cen = cen2; }

    __shared__ float sx0[20], sy0[20], sx1[20], sy1[20], sar[20];
    __shared__ int   slb[20];
    if (threadIdx.x < 20) {
        int k = threadIdx.x;
        const float* bb = boxes + (b * 20 + k) * 4;
        float cx = bb[0] * 512.f, cy = bb[1] * 512.f;
        float w  = bb[2] * 512.f, h  = bb[3] * 512.f;
        float x0 = cx - 0.5f * w, y0 = cy - 0.5f * h;
        float x1 = cx + 0.5f * w, y1 = cy + 0.5f * h;
        sx0[k] = x0; sy0[k] = y0; sx1[k] = x1; sy1[k] = y1;
        sar[k] = (x1 - x0) * (y1 - y0);
        slb[k] = labels[b * 20 + k];
    }
    __syncthreads();

    const float* clsb = cls + (size_t)b * 5 * L;
    const float* regb = reg + (size_t)b * 4 * L;
    const float* cenb = cen + (size_t)b * L;
    const float inv = 1.f / stride;

    float cls_s = 0.f, reg_s = 0.f, cen_s = 0.f, np = 0.f;
    for (int l = threadIdx.x; l < L; l += 256) {
        float lx = ((l & (Wd - 1)) + 0.5f) * stride;
        float ly = ((l >> shift)   + 0.5f) * stride;
        int bk = -1; float ba = INFINITY;
        float bl = 0.f, btp = 0.f, brr = 0.f, bbt = 0.f;
#pragma unroll
        for (int k = 0; k < 20; k++) {
            float li = lx - sx0[k], ti = ly - sy0[k];
            float ri = sx1[k] - lx, bi = sy1[k] - ly;
            float mn = fminf(fminf(li, ti), fminf(ri, bi));
            if (mn > 0.f && sar[k] < ba) {   // strict '<' == first-occurrence argmin
                ba = sar[k]; bk = k;
                bl = li; btp = ti; brr = ri; bbt = bi;
            }
        }
        int tl = (bk >= 0) ? slb[bk] : -1;
#pragma unroll
        for (int c = 0; c < 4; c++) {
            float x = clsb[(c + 1) * L + l];   // channel 0 dropped by reference
            cls_s += focal_elt(x, (c == tl) ? 1.f : 0.f);
        }
        if (bk >= 0) {
            float r0 = bl * inv, r1 = btp * inv, r2 = brr * inv, r3 = bbt * inv;
            float d0 = regb[0 * L + l] - r0;
            float d1 = regb[1 * L + l] - r1;
            float d2 = regb[2 * L + l] - r2;
            float d3 = regb[3 * L + l] - r3;
            float a0 = fabsf(d0), a1 = fabsf(d1), a2 = fabsf(d2), a3 = fabsf(d3);
            float sl = (a0 < 1.f ? 0.5f * d0 * d0 : a0 - 0.5f)
                     + (a1 < 1.f ? 0.5f * d1 * d1 : a1 - 0.5f)
                     + (a2 < 1.f ? 0.5f * d2 * d2 : a2 - 0.5f)
                     + (a3 < 1.f ? 0.5f * d3 * d3 : a3 - 0.5f);
            reg_s += 0.25f * sl;
            float mnlr = fminf(r0, r2), mxlr = fmaxf(r0, r2);
            float mntb = fminf(r1, r3), mxtb = fmaxf(r1, r3);
            float v = (mnlr / (mxlr + 1e-6f)) * (mntb / (mxtb + 1e-6f));
            v = fminf(fmaxf(v, 0.f), 1.f);
            float ct = sqrtf(v);
            cen_s += bce_logits(cenb[l], ct);
            np += 1.f;
        }
    }

    float v4[4] = {cls_s, reg_s, cen_s, np};
    blk_reduce_arr<4>(v4);
    if (threadIdx.x == 0) {
        float cls_l = v4[0] / (L * 4.f);
        float npos  = v4[3];
        float denom = fmaxf(npos, 1.f);
        float reg_l = (npos > 0.f) ? v4[1] / denom : 0.f;
        float cen_l = (npos > 0.f) ? v4[2] / denom : 0.f;
        detc[blockIdx.x] = (cls_l + reg_l + cen_l) * (1.f / (float)DET_BLOCKS);
    }
}

// ---------- final combine: all terms pre-scaled, one accumulator ----------

__global__ __launch_bounds__(256) void final_kernel(
        const float* __restrict__ segpart, const float* __restrict__ detc,
        const float* __restrict__ cls_pred, const int* __restrict__ cls_target,
        float* __restrict__ out) {
    const float seg_scale = 1.f / 33554432.f;   // B*4*512*512 (2^-25, exact)
    const float cls_scale = 0.5f / 320.f;       // W_CLS / (B*10)
    float acc = 0.f;
    for (int i = threadIdx.x; i < SEG_BLOCKS; i += 256) acc += segpart[i] * seg_scale;
    if (threadIdx.x < DET_BLOCKS) acc += detc[threadIdx.x];
    for (int e = threadIdx.x; e < NB * 10; e += 256) {
        int i = e / 10, c = e - i * 10;
        acc += cls_scale * focal_elt(cls_pred[e], (cls_target[i] == c) ? 1.f : 0.f);
    }
    float v[1] = {acc};
    blk_reduce_arr<1>(v);
    if (threadIdx.x == 0) out[0] = v[0];
}

// ---------- launch ----------

extern "C" void kernel_launch(void* const* d_in, const int* in_sizes, int n_in,
                              void* d_out, int out_size, void* d_ws, size_t ws_size,
                              hipStream_t stream) {
    const float* seg_logits = (const float*)d_in[0];
    const int*   seg_mask   = (const int*)d_in[1];
    const float* cls0 = (const float*)d_in[2];
    const float* cls1 = (const float*)d_in[3];
    const float* cls2 = (const float*)d_in[4];
    const float* reg0 = (const float*)d_in[5];
    const float* reg1 = (const float*)d_in[6];
    const float* reg2 = (const float*)d_in[7];
    const float* cen0 = (const float*)d_in[8];
    const float* cen1 = (const float*)d_in[9];
    const float* cen2 = (const float*)d_in[10];
    const float* boxes  = (const float*)d_in[11];
    const int*   labels = (const int*)d_in[12];
    const float* cls_pred   = (const float*)d_in[13];
    const int*   cls_target = (const int*)d_in[14];

    float* ws      = (float*)d_ws;
    float* segpart = ws;                 // SEG_BLOCKS floats
    float* detc    = ws + SEG_BLOCKS;    // DET_BLOCKS floats

    seg_kernel<<<SEG_BLOCKS, 256, 0, stream>>>(seg_logits, seg_mask, segpart);
    det_kernel<<<DET_BLOCKS, 256, 0, stream>>>(cls0, cls1, cls2,
                                               reg0, reg1, reg2,
                                               cen0, cen1, cen2,
                                               boxes, labels, detc);
    final_kernel<<<1, 256, 0, stream>>>(segpart, detc, cls_pred, cls_target,
                                        (float*)d_out);
}

// Round 9
// 265.314 us; speedup vs baseline: 1.0226x; 1.0226x over previous
//
#include <hip/hip_runtime.h>
#include <math.h>

#define NB 32            // batch
#define DET_BLOCKS 96    // 3 scales * 32 images
#define SEG_BLOCKS 2048  // 1024 mask-quads (4096 px * 4 ch) per block

typedef float fvec4 __attribute__((ext_vector_type(4)));   // NT-load-compatible

// ---------- math helpers (match reference semantics) ----------

__device__ __forceinline__ float bce_logits(float x, float y) {
    // max(x,0) - x*y + log1p(exp(-|x|))
    float a = fabsf(x);
    return fmaxf(x, 0.f) - x * y + __logf(1.f + __expf(-a));
}

__device__ __forceinline__ float focal_elt(float x, float t) {
    // t is exactly 0.0 or 1.0 (one-hot)
    float p = 1.f / (1.f + __expf(-x));
    float ce = bce_logits(x, t);
    float p_t = (t > 0.5f) ? p : (1.f - p);
    float a_t = (t > 0.5f) ? 0.25f : 0.75f;
    float om = 1.f - p_t;
    return a_t * om * om * ce;
}

// Block reduction for N floats, blockDim.x == 256 (4 waves of 64).
template <int N>
__device__ void blk_reduce_arr(float* v) {
    __shared__ float sm[N][4];
    int lane = threadIdx.x & 63;
    int wid  = threadIdx.x >> 6;
#pragma unroll
    for (int j = 0; j < N; j++) {
        float x = v[j];
#pragma unroll
        for (int off = 32; off > 0; off >>= 1) x += __shfl_down(x, off, 64);
        if (lane == 0) sm[j][wid] = x;
    }
    __syncthreads();
    if (threadIdx.x == 0) {
#pragma unroll
        for (int j = 0; j < N; j++) {
            float s = 0.f;
#pragma unroll
            for (int w = 0; w < 4; w++) s += sm[j][w];
            v[j] = s;
        }
    }
}

// ---------- seg: copy-shaped streaming ----------
// 2048 blocks (8/CU, whole grid co-resident at 32 waves/CU). Block owns 1024
// contiguous mask-quads of one image. Mask staged once to LDS as floats;
// then 4 sequential channel passes, each ONE contiguous 16 KB nontemporal
// float4 stream per block (adjacent blocks -> adjacent addresses).

__global__ __launch_bounds__(256, 8) void seg_kernel(
        const float* __restrict__ logits, const int* __restrict__ mask,
        float* __restrict__ partial) {
    const int HW  = 512 * 512;   // px per image
    const int QPI = HW / 4;      // 65536 quads per image
    __shared__ fvec4 smask[1024];   // 16 KB: block's targets as floats

    const int t = threadIdx.x;
    const size_t qb = (size_t)blockIdx.x * 1024;   // global mask-quad base
    const int b    = (int)(qb >> 16);              // image (1024 | 65536: no straddle)
    const int hwq0 = (int)(qb & 65535);            // quad offset within image

    // Phase 1: stage mask -> LDS (once)
    const int4* mq = (const int4*)(mask + (size_t)b * HW) + hwq0;
#pragma unroll
    for (int i = 0; i < 4; i++) {
        const int4 m = mq[i * 256 + t];
        fvec4 f; f.x = (float)m.x; f.y = (float)m.y;
        f.z = (float)m.z; f.w = (float)m.w;
        smask[i * 256 + t] = f;
    }
    __syncthreads();

    // Phase 2: 4 channel passes, contiguous NT streams
    float acc = 0.f;
    const fvec4* xq = (const fvec4*)(logits + (size_t)b * 4 * HW) + hwq0;
#pragma unroll 1
    for (int c = 0; c < 4; c++) {
        const fvec4* xc = xq + (size_t)c * QPI;
        fvec4 x0 = __builtin_nontemporal_load(xc + 0 * 256 + t);
        fvec4 x1 = __builtin_nontemporal_load(xc + 1 * 256 + t);
        fvec4 x2 = __builtin_nontemporal_load(xc + 2 * 256 + t);
        fvec4 x3 = __builtin_nontemporal_load(xc + 3 * 256 + t);
        fvec4 t0 = smask[0 * 256 + t];
        fvec4 t1 = smask[1 * 256 + t];
        fvec4 t2 = smask[2 * 256 + t];
        fvec4 t3 = smask[3 * 256 + t];
        acc += bce_logits(x0.x, t0.x) + bce_logits(x0.y, t0.y)
             + bce_logits(x0.z, t0.z) + bce_logits(x0.w, t0.w);
        acc += bce_logits(x1.x, t1.x) + bce_logits(x1.y, t1.y)
             + bce_logits(x1.z, t1.z) + bce_logits(x1.w, t1.w);
        acc += bce_logits(x2.x, t2.x) + bce_logits(x2.y, t2.y)
             + bce_logits(x2.z, t2.z) + bce_logits(x2.w, t2.w);
        acc += bce_logits(x3.x, t3.x) + bce_logits(x3.y, t3.y)
             + bce_logits(x3.z, t3.z) + bce_logits(x3.w, t3.w);
    }

    float v[1] = {acc};
    blk_reduce_arr<1>(v);
    if (t == 0) partial[blockIdx.x] = v[0];
}

// ---------- det: standalone, one block per (scale, image) ----------

__global__ __launch_bounds__(256) void det_kernel(
        const float* __restrict__ cls0, const float* __restrict__ cls1, const float* __restrict__ cls2,
        const float* __restrict__ reg0, const float* __restrict__ reg1, const float* __restrict__ reg2,
        const float* __restrict__ cen0, const float* __restrict__ cen1, const float* __restrict__ cen2,
        const float* __restrict__ boxes, const int* __restrict__ labels,
        float* __restrict__ detc) {
    const int s = blockIdx.x >> 5;   // 0..2
    const int b = blockIdx.x & 31;   // 0..31
    int Wd, shift, L; float stride;
    const float *cls, *reg, *cen;
    if (s == 0)      { Wd = 64; shift = 6; L = 4096; stride = 8.f;  cls = cls0; reg = reg0; cen = cen0; }
    else if (s == 1) { Wd = 32; shift = 5; L = 1024; stride = 16.f; cls = cls1; reg = reg1; cen = cen1; }
    else             { Wd = 16; shift = 4; L = 256;  stride = 32.f; cls = cls2; reg = reg2; cen = cen2; }

    __shared__ float sx0[20], sy0[20], sx1[20], sy1[20], sar[20];
    __shared__ int   slb[20];
    if (threadIdx.x < 20) {
        int k = threadIdx.x;
        const float* bb = boxes + (b * 20 + k) * 4;
        float cx = bb[0] * 512.f, cy = bb[1] * 512.f;
        float w  = bb[2] * 512.f, h  = bb[3] * 512.f;
        float x0 = cx - 0.5f * w, y0 = cy - 0.5f * h;
        float x1 = cx + 0.5f * w, y1 = cy + 0.5f * h;
        sx0[k] = x0; sy0[k] = y0; sx1[k] = x1; sy1[k] = y1;
        sar[k] = (x1 - x0) * (y1 - y0);
        slb[k] = labels[b * 20 + k];
    }
    __syncthreads();

    const float* clsb = cls + (size_t)b * 5 * L;
    const float* regb = reg + (size_t)b * 4 * L;
    const float* cenb = cen + (size_t)b * L;
    const float inv = 1.f / stride;

    float cls_s = 0.f, reg_s = 0.f, cen_s = 0.f, np = 0.f;
    for (int l = threadIdx.x; l < L; l += 256) {
        float lx = ((l & (Wd - 1)) + 0.5f) * stride;
        float ly = ((l >> shift)   + 0.5f) * stride;
        int bk = -1; float ba = INFINITY;
        float bl = 0.f, btp = 0.f, brr = 0.f, bbt = 0.f;
#pragma unroll
        for (int k = 0; k < 20; k++) {
            float li = lx - sx0[k], ti = ly - sy0[k];
            float ri = sx1[k] - lx, bi = sy1[k] - ly;
            float mn = fminf(fminf(li, ti), fminf(ri, bi));
            if (mn > 0.f && sar[k] < ba) {   // strict '<' == first-occurrence argmin
                ba = sar[k]; bk = k;
                bl = li; btp = ti; brr = ri; bbt = bi;
            }
        }
        int tl = (bk >= 0) ? slb[bk] : -1;
#pragma unroll
        for (int c = 0; c < 4; c++) {
            float x = clsb[(c + 1) * L + l];   // channel 0 dropped by reference
            cls_s += focal_elt(x, (c == tl) ? 1.f : 0.f);
        }
        if (bk >= 0) {
            float r0 = bl * inv, r1 = btp * inv, r2 = brr * inv, r3 = bbt * inv;
            float d0 = regb[0 * L + l] - r0;
            float d1 = regb[1 * L + l] - r1;
            float d2 = regb[2 * L + l] - r2;
            float d3 = regb[3 * L + l] - r3;
            float a0 = fabsf(d0), a1 = fabsf(d1), a2 = fabsf(d2), a3 = fabsf(d3);
            float sl = (a0 < 1.f ? 0.5f * d0 * d0 : a0 - 0.5f)
                     + (a1 < 1.f ? 0.5f * d1 * d1 : a1 - 0.5f)
                     + (a2 < 1.f ? 0.5f * d2 * d2 : a2 - 0.5f)
                     + (a3 < 1.f ? 0.5f * d3 * d3 : a3 - 0.5f);
            reg_s += 0.25f * sl;
            float mnlr = fminf(r0, r2), mxlr = fmaxf(r0, r2);
            float mntb = fminf(r1, r3), mxtb = fmaxf(r1, r3);
            float v = (mnlr / (mxlr + 1e-6f)) * (mntb / (mxtb + 1e-6f));
            v = fminf(fmaxf(v, 0.f), 1.f);
            float ct = sqrtf(v);
            cen_s += bce_logits(cenb[l], ct);
            np += 1.f;
        }
    }

    float v4[4] = {cls_s, reg_s, cen_s, np};
    blk_reduce_arr<4>(v4);
    if (threadIdx.x == 0) {
        float cls_l = v4[0] / (L * 4.f);
        float npos  = v4[3];
        float denom = fmaxf(npos, 1.f);
        float reg_l = (npos > 0.f) ? v4[1] / denom : 0.f;
        float cen_l = (npos > 0.f) ? v4[2] / denom : 0.f;
        detc[blockIdx.x] = (cls_l + reg_l + cen_l) * (1.f / (float)DET_BLOCKS);
    }
}

// ---------- final combine: all terms pre-scaled, one accumulator ----------

__global__ __launch_bounds__(256) void final_kernel(
        const float* __restrict__ segpart, const float* __restrict__ detc,
        const float* __restrict__ cls_pred, const int* __restrict__ cls_target,
        float* __restrict__ out) {
    const float seg_scale = 1.f / 33554432.f;   // B*4*512*512 (2^-25, exact)
    const float cls_scale = 0.5f / 320.f;       // W_CLS / (B*10)
    float acc = 0.f;
    for (int i = threadIdx.x; i < SEG_BLOCKS; i += 256) acc += segpart[i] * seg_scale;
    if (threadIdx.x < DET_BLOCKS) acc += detc[threadIdx.x];
    for (int e = threadIdx.x; e < NB * 10; e += 256) {
        int i = e / 10, c = e - i * 10;
        acc += cls_scale * focal_elt(cls_pred[e], (cls_target[i] == c) ? 1.f : 0.f);
    }
    float v[1] = {acc};
    blk_reduce_arr<1>(v);
    if (threadIdx.x == 0) out[0] = v[0];
}

// ---------- launch ----------

extern "C" void kernel_launch(void* const* d_in, const int* in_sizes, int n_in,
                              void* d_out, int out_size, void* d_ws, size_t ws_size,
                              hipStream_t stream) {
    const float* seg_logits = (const float*)d_in[0];
    const int*   seg_mask   = (const int*)d_in[1];
    const float* cls0 = (const float*)d_in[2];
    const float* cls1 = (const float*)d_in[3];
    const float* cls2 = (const float*)d_in[4];
    const float* reg0 = (const float*)d_in[5];
    const float* reg1 = (const float*)d_in[6];
    const float* reg2 = (const float*)d_in[7];
    const float* cen0 = (const float*)d_in[8];
    const float* cen1 = (const float*)d_in[9];
    const float* cen2 = (const float*)d_in[10];
    const float* boxes  = (const float*)d_in[11];
    const int*   labels = (const int*)d_in[12];
    const float* cls_pred   = (const float*)d_in[13];
    const int*   cls_target = (const int*)d_in[14];

    float* ws      = (float*)d_ws;
    float* segpart = ws;                 // SEG_BLOCKS floats
    float* detc    = ws + SEG_BLOCKS;    // DET_BLOCKS floats

    seg_kernel<<<SEG_BLOCKS, 256, 0, stream>>>(seg_logits, seg_mask, segpart);
    det_kernel<<<DET_BLOCKS, 256, 0, stream>>>(cls0, cls1, cls2,
                                               reg0, reg1, reg2,
                                               cen0, cen1, cen2,
                                               boxes, labels, detc);
    final_kernel<<<1, 256, 0, stream>>>(segpart, detc, cls_pred, cls_target,
                                        (float*)d_out);
}